// Round 1
// baseline (80.054 us; speedup 1.0000x reference)
//
#include <hip/hip_runtime.h>
#include <stdint.h>

// ---------------------------------------------------------------------------
// BareKANLayer: out[b,o] = sum_d PCHIP_interp(x[b,d]; coeffs[o,d,:]) + bias[o]
// B=8192, O=64, D=64, K=64, grid [-2,2], h = 4/63.
//
// Table formulation: per (d, interval i, o) store cubic coeffs c0..c3 of
//   p(u) = c0 + c1 u + c2 u^2 + c3 u^3   (u = t - i, t = (x+2)/h)
// packed as bf16 in a uint2: .x = (bf(c1)<<16)|bf(c0), .y = (bf(c3)<<16)|bf(c2)
// Row i=63 is a special LINEAR row for right extrapolation:
//   .x = (bf(h*dN)<<16)|bf(yN), .y = 0   -> value = yN + h*dN*(t-63)
// Left extrapolation reuses row 0 (c0=y0, c1=h*d0) with w2=w3=0.
// Per-(b,d) weight record: (w1,w2,w3, byte-offset of row) ->
//   contribution to all o: c0 + c1*w1 + c2*w2 + c3*w3  (c0 weight is 1).
// Table: 64 slices x (64 rows x 64 o x 8B) = 64 x 32768 B = 2 MB in d_ws.
// ---------------------------------------------------------------------------

__device__ __forceinline__ uint32_t bf16r(float f) {
    uint32_t u = __float_as_uint(f);
    return (u + 0x7fffu + ((u >> 16) & 1u)) >> 16;   // RNE; no NaN/Inf here
}

// Grid: 256 blocks (d = bx>>2, o-quarter = bx&3), 256 threads.
__global__ void build_table(const float* __restrict__ coeffs, uint2* __restrict__ T) {
    const float hf = 4.0f / 63.0f;
    const float inv_hf = 63.0f / 4.0f;   // 15.75 exact in fp32
    int d  = blockIdx.x >> 2;
    int ob = (blockIdx.x & 3) << 4;      // base of this block's 16 o's
    __shared__ float Y[16][65];          // +1 pad: conflict-free
    int t = threadIdx.x;
    {
        int ol = t >> 4;                 // 0..15  (o local)
        int k4 = (t & 15) << 2;          // 0,4,...,60
        const float* src = coeffs + (size_t)(ob + ol) * 4096 + d * 64 + k4;
        float4 v = *(const float4*)src;  // 16B aligned
        Y[ol][k4 + 0] = v.x; Y[ol][k4 + 1] = v.y;
        Y[ol][k4 + 2] = v.z; Y[ol][k4 + 3] = v.w;
    }
    __syncthreads();
    for (int c = t; c < 1024; c += 256) {
        int ol = c & 15;
        int i  = c >> 4;                 // 0..63 (63 = linear extrapolation row)
        const float* Yr = Y[ol];
        auto delt = [&](int k) -> float { return (Yr[k + 1] - Yr[k]) * inv_hf; };
        auto endslope = [&](float a, float b) -> float {
            // a = boundary delta, b = next-inner delta; mirrors reference exactly
            float de = (3.0f * a - b) * 0.5f;
            de = (de * a <= 0.0f) ? 0.0f : de;
            de = ((a * b < 0.0f) && (fabsf(de) > 3.0f * fabsf(a))) ? 3.0f * a : de;
            return de;
        };
        auto slope = [&](int k) -> float {
            if (k == 0)  return endslope(delt(0), delt(1));
            if (k == 63) return endslope(delt(62), delt(61));
            float dp = delt(k - 1), dn = delt(k);
            return (dp * dn > 0.0f) ? (2.0f * dp * dn) / (dp + dn + 1e-12f) : 0.0f;
        };
        uint2 pk;
        if (i < 63) {
            float y0 = Yr[i], y1 = Yr[i + 1];
            float di = slope(i), dj = slope(i + 1);
            float c0 = y0;
            float c1 = hf * di;
            float c2 = 3.0f * (y1 - y0) - hf * (2.0f * di + dj);
            float c3 = 2.0f * (y0 - y1) + hf * (di + dj);
            pk.x = (bf16r(c1) << 16) | bf16r(c0);
            pk.y = (bf16r(c3) << 16) | bf16r(c2);
        } else {
            float yN = Yr[63];
            float dN = slope(63);
            pk.x = (bf16r(hf * dN) << 16) | bf16r(yN);
            pk.y = 0u;
        }
        T[(size_t)d * 4096 + i * 64 + (ob + ol)] = pk;
    }
}

// Grid: 512 blocks x 1024 threads (16 waves). Block owns 16 rows x all 64 d.
// Wave w: rowq = w&3 (4 rows), dq = w>>2 (16 d's). lane = o.
// Phase 1: 1024 weight records into LDS. Phase 2: gather+FMA. Phase 3: LDS reduce.
__global__ void __launch_bounds__(1024) kan_main(const float* __restrict__ x,
                                                 const float* __restrict__ bias,
                                                 const char* __restrict__ Tb,
                                                 float* __restrict__ out) {
    __shared__ uint4 WrecL[1024];        // 16 KB; overlaid by Obuf in epilogue
    const float hf = 4.0f / 63.0f;
    int t  = threadIdx.x;
    int bx = blockIdx.x;

    // ---- phase 1: per-(row,d) weight records ----
    {
        float xv = x[(size_t)bx * 1024 + t];          // (b = bx*16 + t>>6, d = t&63)
        float tt = (xv + 2.0f) / hf;
        int i = (int)floorf(tt);
        i = i < 0 ? 0 : (i > 62 ? 62 : i);
        float u = tt - (float)i;
        float w1, w2, w3; uint32_t off;
        if (xv < -2.0f)      { w1 = tt;          w2 = 0.0f;  w3 = 0.0f;  off = 0u; }
        else if (xv > 2.0f)  { w1 = tt - 63.0f;  w2 = 0.0f;  w3 = 0.0f;  off = 63u << 9; }
        else                 { w1 = u;           w2 = u * u; w3 = w2 * u; off = (uint32_t)i << 9; }
        WrecL[t] = make_uint4(__float_as_uint(w1), __float_as_uint(w2),
                              __float_as_uint(w3), off);
    }
    __syncthreads();

    // ---- phase 2: accumulate ----
    int w    = __builtin_amdgcn_readfirstlane(t >> 6);   // force wave-uniform
    int lane = t & 63;
    int rowq = w & 3;
    int dq   = w >> 2;
    int laneoff = lane << 3;
    float acc0 = 0.f, acc1 = 0.f, acc2 = 0.f, acc3 = 0.f;
    const char* slice = Tb + (size_t)dq * 16 * 32768;
    int wbase = rowq * 4 * 64 + (dq << 4);
    for (int dd = 0; dd < 16; ++dd) {
        uint4 q0 = WrecL[wbase + 0 * 64 + dd];
        uint4 q1 = WrecL[wbase + 1 * 64 + dd];
        uint4 q2 = WrecL[wbase + 2 * 64 + dd];
        uint4 q3 = WrecL[wbase + 3 * 64 + dd];
        uint2 p0 = *(const uint2*)(slice + q0.w + laneoff);
        uint2 p1 = *(const uint2*)(slice + q1.w + laneoff);
        uint2 p2 = *(const uint2*)(slice + q2.w + laneoff);
        uint2 p3 = *(const uint2*)(slice + q3.w + laneoff);

        acc0 += __uint_as_float(p0.x << 16);
        acc0 = fmaf(__uint_as_float(q0.x), __uint_as_float(p0.x & 0xffff0000u), acc0);
        acc0 = fmaf(__uint_as_float(q0.y), __uint_as_float(p0.y << 16),         acc0);
        acc0 = fmaf(__uint_as_float(q0.z), __uint_as_float(p0.y & 0xffff0000u), acc0);

        acc1 += __uint_as_float(p1.x << 16);
        acc1 = fmaf(__uint_as_float(q1.x), __uint_as_float(p1.x & 0xffff0000u), acc1);
        acc1 = fmaf(__uint_as_float(q1.y), __uint_as_float(p1.y << 16),         acc1);
        acc1 = fmaf(__uint_as_float(q1.z), __uint_as_float(p1.y & 0xffff0000u), acc1);

        acc2 += __uint_as_float(p2.x << 16);
        acc2 = fmaf(__uint_as_float(q2.x), __uint_as_float(p2.x & 0xffff0000u), acc2);
        acc2 = fmaf(__uint_as_float(q2.y), __uint_as_float(p2.y << 16),         acc2);
        acc2 = fmaf(__uint_as_float(q2.z), __uint_as_float(p2.y & 0xffff0000u), acc2);

        acc3 += __uint_as_float(p3.x << 16);
        acc3 = fmaf(__uint_as_float(q3.x), __uint_as_float(p3.x & 0xffff0000u), acc3);
        acc3 = fmaf(__uint_as_float(q3.y), __uint_as_float(p3.y << 16),         acc3);
        acc3 = fmaf(__uint_as_float(q3.z), __uint_as_float(p3.y & 0xffff0000u), acc3);

        slice += 32768;
    }
    __syncthreads();   // all WrecL reads done before overlay

    // ---- phase 3: reduce the 4 d-quarters via LDS, write out ----
    float* Obuf = (float*)WrecL;          // 4 x 1024 floats = 16 KB
    int obase = dq * 1024 + rowq * 4 * 64 + lane;
    Obuf[obase + 0 * 64] = acc0;
    Obuf[obase + 1 * 64] = acc1;
    Obuf[obase + 2 * 64] = acc2;
    Obuf[obase + 3 * 64] = acc3;
    __syncthreads();
    float s = Obuf[t] + Obuf[1024 + t] + Obuf[2048 + t] + Obuf[3072 + t];
    out[(size_t)bx * 1024 + t] = s + bias[t & 63];
}

extern "C" void kernel_launch(void* const* d_in, const int* in_sizes, int n_in,
                              void* d_out, int out_size, void* d_ws, size_t ws_size,
                              hipStream_t stream) {
    const float* x      = (const float*)d_in[0];   // [8192, 64]
    const float* coeffs = (const float*)d_in[1];   // [64, 64, 64]
    const float* bias   = (const float*)d_in[2];   // [64]
    float* out = (float*)d_out;                    // [8192, 64]

    uint2* T = (uint2*)d_ws;                       // 2 MB table
    build_table<<<dim3(256), dim3(256), 0, stream>>>(coeffs, T);
    kan_main<<<dim3(512), dim3(1024), 0, stream>>>(x, bias, (const char*)d_ws, out);
}

// Round 2
// 78.575 us; speedup vs baseline: 1.0188x; 1.0188x over previous
//
#include <hip/hip_runtime.h>
#include <hip/hip_fp16.h>
#include <stdint.h>

// ---------------------------------------------------------------------------
// BareKANLayer: out[b,o] = sum_d PCHIP_interp(x[b,d]; coeffs[o,d,:]) + bias[o]
// B=8192, O=64, D=64, K=64, grid [-2,2], h = 4/63.
//
// Table: per (d, interval i, o) cubic coeffs of p(u) = c0 + c1 u + c2 u^2 + c3 u^3
// packed as fp16 in a uint2: .x = (h(c1)<<16)|h(c0), .y = (h(c3)<<16)|h(c2).
// Row i=63 is a LINEAR row for right extrapolation: .x = (h(h*dN)<<16)|h(yN), .y=0.
// Left extrapolation reuses row 0 with w2=w3=0.
// Layout: T[d][i][o], slice per d = 64*64*8 = 32 KB, total 2 MB in d_ws.
//
// Main kernel: one wave per b (lane = o). Per-lane (lane = d) weight records
// (h2(1,w1), h2(w2,w3), byte-offset) staged in LDS; d-loop does one uniform
// ds_read_b128 + one coalesced 512B L2 gather + two v_dot2_f32_f16 per d.
// ---------------------------------------------------------------------------

typedef _Float16 half2v __attribute__((ext_vector_type(2)));

#if defined(__has_builtin)
#if __has_builtin(__builtin_amdgcn_fdot2)
#define HAS_FDOT2 1
#endif
#endif

__device__ __forceinline__ uint32_t h16(float f) {
    return (uint32_t)__half_as_ushort(__float2half(f));   // RNE cvt
}

__device__ __forceinline__ float dot2acc(uint32_t a_bits, uint32_t b_bits, float acc) {
    half2v a = __builtin_bit_cast(half2v, a_bits);
    half2v b = __builtin_bit_cast(half2v, b_bits);
#ifdef HAS_FDOT2
    return __builtin_amdgcn_fdot2(a, b, acc, false);
#else
    return acc + (float)a.x * (float)b.x + (float)a.y * (float)b.y;
#endif
}

// Grid: 256 blocks (d = bx>>2, o-quarter = bx&3), 256 threads.
__global__ void build_table(const float* __restrict__ coeffs, uint2* __restrict__ T) {
    const float hf = 4.0f / 63.0f;
    const float inv_hf = 63.0f / 4.0f;   // 15.75 exact in fp32
    int d  = blockIdx.x >> 2;
    int ob = (blockIdx.x & 3) << 4;      // base of this block's 16 o's
    __shared__ float Y[16][65];          // +1 pad: conflict-free
    int t = threadIdx.x;
    {
        int ol = t >> 4;                 // 0..15  (o local)
        int k4 = (t & 15) << 2;          // 0,4,...,60
        const float* src = coeffs + (size_t)(ob + ol) * 4096 + d * 64 + k4;
        float4 v = *(const float4*)src;  // 16B aligned
        Y[ol][k4 + 0] = v.x; Y[ol][k4 + 1] = v.y;
        Y[ol][k4 + 2] = v.z; Y[ol][k4 + 3] = v.w;
    }
    __syncthreads();
    for (int c = t; c < 1024; c += 256) {
        int ol = c & 15;
        int i  = c >> 4;                 // 0..63 (63 = linear extrapolation row)
        const float* Yr = Y[ol];
        auto delt = [&](int k) -> float { return (Yr[k + 1] - Yr[k]) * inv_hf; };
        auto endslope = [&](float a, float b) -> float {
            float de = (3.0f * a - b) * 0.5f;
            de = (de * a <= 0.0f) ? 0.0f : de;
            de = ((a * b < 0.0f) && (fabsf(de) > 3.0f * fabsf(a))) ? 3.0f * a : de;
            return de;
        };
        auto slope = [&](int k) -> float {
            if (k == 0)  return endslope(delt(0), delt(1));
            if (k == 63) return endslope(delt(62), delt(61));
            float dp = delt(k - 1), dn = delt(k);
            return (dp * dn > 0.0f) ? (2.0f * dp * dn) / (dp + dn + 1e-12f) : 0.0f;
        };
        uint2 pk;
        if (i < 63) {
            float y0 = Yr[i], y1 = Yr[i + 1];
            float di = slope(i), dj = slope(i + 1);
            float c0 = y0;
            float c1 = hf * di;
            float c2 = 3.0f * (y1 - y0) - hf * (2.0f * di + dj);
            float c3 = 2.0f * (y0 - y1) + hf * (di + dj);
            pk.x = (h16(c1) << 16) | h16(c0);
            pk.y = (h16(c3) << 16) | h16(c2);
        } else {
            float yN = Yr[63];
            float dN = slope(63);
            pk.x = (h16(hf * dN) << 16) | h16(yN);
            pk.y = 0u;
        }
        T[(size_t)d * 4096 + i * 64 + (ob + ol)] = pk;
    }
}

// Grid: 2048 blocks x 256 threads (4 waves). Wave wv owns b = bx*4+wv; lane = o.
__global__ void __launch_bounds__(256) kan_main(const float* __restrict__ x,
                                                const float* __restrict__ bias,
                                                const char* __restrict__ Tb,
                                                float* __restrict__ out) {
    __shared__ uint4 WL[256];            // 4 KB: 4 waves x 64 records
    int t    = threadIdx.x;
    int lane = t & 63;
    int wv   = t >> 6;
    int b    = blockIdx.x * 4 + wv;

    // ---- weight record for (b, d=lane) ----
    {
        float xv = x[b * 64 + lane];
        float tt = (xv + 2.0f) * 15.75f;
        int i = (int)floorf(tt);
        i = i < 0 ? 0 : (i > 62 ? 62 : i);
        float u = tt - (float)i;
        float w1, w2, w3; uint32_t off;
        if (xv < -2.0f)      { w1 = tt;          w2 = 0.f;    w3 = 0.f;    off = 0u; }
        else if (xv > 2.0f)  { w1 = tt - 63.0f;  w2 = 0.f;    w3 = 0.f;    off = 63u << 9; }
        else                 { w1 = u;           w2 = u * u;  w3 = w2 * u; off = (uint32_t)i << 9; }
        half2v wa; wa.x = (_Float16)1.0f; wa.y = (_Float16)w1;
        half2v wb; wb.x = (_Float16)w2;   wb.y = (_Float16)w3;
        uint32_t full_off = ((uint32_t)lane << 15) | off;   // lane*32768 + i*512
        WL[t] = make_uint4(__builtin_bit_cast(uint32_t, wa),
                           __builtin_bit_cast(uint32_t, wb), full_off, 0u);
    }
    __syncthreads();

    // ---- accumulate over d ----
    float acc0 = bias[lane];
    float acc1 = 0.0f;
    int laneoff = lane << 3;
    const uint4* wl = &WL[wv << 6];
    #pragma unroll 8
    for (int d = 0; d < 64; ++d) {
        uint4 q = wl[d];                                        // uniform -> broadcast
        uint32_t off = __builtin_amdgcn_readfirstlane(q.z);     // force SGPR base
        uint2 c = *(const uint2*)(Tb + off + laneoff);          // 512B coalesced, L2-hot
        acc0 = dot2acc(q.x, c.x, acc0);
        acc1 = dot2acc(q.y, c.y, acc1);
    }
    out[b * 64 + lane] = acc0 + acc1;
}

extern "C" void kernel_launch(void* const* d_in, const int* in_sizes, int n_in,
                              void* d_out, int out_size, void* d_ws, size_t ws_size,
                              hipStream_t stream) {
    const float* x      = (const float*)d_in[0];   // [8192, 64]
    const float* coeffs = (const float*)d_in[1];   // [64, 64, 64]
    const float* bias   = (const float*)d_in[2];   // [64]
    float* out = (float*)d_out;                    // [8192, 64]

    uint2* T = (uint2*)d_ws;                       // 2 MB table
    build_table<<<dim3(256), dim3(256), 0, stream>>>(coeffs, T);
    kan_main<<<dim3(2048), dim3(256), 0, stream>>>(x, bias, (const char*)d_ws, out);
}